// Round 1
// baseline (783.661 us; speedup 1.0000x reference)
//
#include <hip/hip_runtime.h>
#include <math.h>

// GraphQNetwork: 2-layer GAT (H=4 heads, C=64, concat=False/head-mean) + 3 FC + per-graph min.
// N=50000, E=400000, NG=64 (derived from in_sizes at launch).

__device__ __forceinline__ float gelu_f(float x){
    return 0.5f * x * (1.0f + erff(x * 0.70710678118654752f));
}

// ---------------- edge stats (mean of modified edge_attr) + in-degree histogram ----------------
__global__ void k_edge_stats(const int* __restrict__ ei, const float* __restrict__ ea,
                             int E, double* __restrict__ dsum, int* __restrict__ deg){
    __shared__ double s0[256], s1[256], s2[256];
    int t = threadIdx.x;
    double a0 = 0, a1 = 0, a2 = 0;
    for (int e = blockIdx.x * blockDim.x + t; e < E; e += gridDim.x * blockDim.x){
        float e0 = ea[e*3+0], e1 = ea[e*3+1], e2 = ea[e*3+2];
        a0 += (double)e0;
        a1 += (double)e1;
        a2 += 1.0e6 / (double)e2;   // in-place edit: 1e6 / spectral_efficiency
        atomicAdd(&deg[ei[E + e]], 1);   // dst = edge_index[1]
    }
    s0[t] = a0; s1[t] = a1; s2[t] = a2;
    __syncthreads();
    for (int off = 128; off > 0; off >>= 1){
        if (t < off){ s0[t] += s0[t+off]; s1[t] += s1[t+off]; s2[t] += s2[t+off]; }
        __syncthreads();
    }
    if (t == 0){
        atomicAdd(&dsum[0], s0[0]);
        atomicAdd(&dsum[1], s1[0]);
        atomicAdd(&dsum[2], s2[0]);
    }
}

// ---------------- tiny parameter precompute ----------------
// M[l][j][h]      = sum_c We[l,j,h*64+c] * attE[l,h,c]            (double)
// ael[l][h]       = sum_j mean_j * M[l][j][h]                     (double)
// Wsrc[l][k][h]   = sum_c W[l,k,h*64+c] * attS[l,h,c]             (float)
// Wdst[l][k][h]   = sum_c W[l,k,h*64+c] * attD[l,h,c]             (float)
// Wt[l][h*64+k][c]= 0.25 * W[l,k,h*64+c]                          (float; head-mean folded)
__global__ void k_params(const double* __restrict__ dsum, int E,
                         const float* __restrict__ convW, const float* __restrict__ attS,
                         const float* __restrict__ attD, const float* __restrict__ We,
                         const float* __restrict__ attE,
                         double* __restrict__ Mm, double* __restrict__ ael,
                         float* __restrict__ Wsrc, float* __restrict__ Wdst,
                         float* __restrict__ Wt){
    int t = threadIdx.x;
    if (t < 24){
        int l = t / 12, r = t % 12, j = r / 4, h = r % 4;
        double s = 0;
        for (int c = 0; c < 64; c++)
            s += (double)We[l*768 + j*256 + h*64 + c] * (double)attE[l*256 + h*64 + c];
        Mm[l*12 + j*4 + h] = s;
    }
    __syncthreads();
    if (t < 8){
        int l = t / 4, h = t % 4;
        double s = 0;
        for (int j = 0; j < 3; j++)
            s += (dsum[j] / (double)E) * Mm[l*12 + j*4 + h];
        ael[l*4 + h] = s;
    }
    for (int idx = t; idx < 512; idx += 256){
        int l = idx >> 8, k = (idx >> 2) & 63, h = idx & 3;
        float ss = 0.f, sd = 0.f;
        for (int c = 0; c < 64; c++){
            float wv = convW[l*16384 + k*256 + h*64 + c];
            ss += wv * attS[l*256 + h*64 + c];
            sd += wv * attD[l*256 + h*64 + c];
        }
        Wsrc[idx] = ss; Wdst[idx] = sd;
    }
    for (int idx = t; idx < 32768; idx += 256){
        int l = idx >> 14, p = (idx >> 6) & 255, c = idx & 63;
        int h = p >> 6, k = p & 63;
        Wt[idx] = 0.25f * convW[l*16384 + k*256 + h*64 + c];
    }
}

// ---------------- CSR build: chunk sums -> chunk scan -> row_ptr -> scatter ----------------
__global__ void k_chunk_sum(const int* __restrict__ deg, int n, int* __restrict__ csum){
    __shared__ int s[256];
    int t = threadIdx.x, base = blockIdx.x * 1024;
    int v = 0;
    for (int j = t; j < 1024; j += 256){ int i = base + j; if (i < n) v += deg[i]; }
    s[t] = v; __syncthreads();
    for (int off = 128; off > 0; off >>= 1){ if (t < off) s[t] += s[t+off]; __syncthreads(); }
    if (t == 0) csum[blockIdx.x] = s[0];
}

__global__ void k_chunk_scan(const int* __restrict__ csum, int nchunks,
                             int* __restrict__ coff, int* __restrict__ rp_end){
    if (threadIdx.x == 0){
        int run = 0;
        for (int i = 0; i < nchunks; i++){ coff[i] = run; run += csum[i]; }
        *rp_end = run;
    }
}

__global__ void __launch_bounds__(1024) k_row_ptr(const int* __restrict__ deg, int n,
                          const int* __restrict__ coff,
                          int* __restrict__ row_ptr, int* __restrict__ cursor){
    __shared__ int s[1024];
    int t = threadIdx.x, i = blockIdx.x * 1024 + t;
    int v = (i < n) ? deg[i] : 0;
    s[t] = v; __syncthreads();
    for (int off = 1; off < 1024; off <<= 1){
        int x = (t >= off) ? s[t-off] : 0;
        __syncthreads();
        s[t] += x;
        __syncthreads();
    }
    if (i < n){
        int e = coff[blockIdx.x] + s[t] - v;   // exclusive
        row_ptr[i] = e; cursor[i] = e;
    }
}

__global__ void k_scatter(const int* __restrict__ ei, int E, int* __restrict__ cursor,
                          int* __restrict__ col_src, int* __restrict__ col_eid){
    for (int e = blockIdx.x * blockDim.x + threadIdx.x; e < E; e += gridDim.x * blockDim.x){
        int d = ei[E + e];
        int pos = atomicAdd(&cursor[d], 1);
        col_src[pos] = ei[e];
        col_eid[pos] = e;
    }
}

// ---------------- input projection: h = gelu(x @ linW + linb), D_IN=15 ----------------
__global__ void k_lin_in(const float* __restrict__ x, const float* __restrict__ W,
                         const float* __restrict__ b, float* __restrict__ h, int n){
    int t = threadIdx.x;
    int row = blockIdx.x * 4 + (t >> 6);
    int c = t & 63;
    if (row >= n) return;
    float acc = b[c];
    #pragma unroll
    for (int j = 0; j < 15; j++) acc += x[row*15 + j] * W[j*64 + c];
    h[row*64 + c] = gelu_f(acc);
}

// ---------------- attention coefficients: a_src/a_dst = h @ Wsrc/Wdst ([64,4]) ----------------
__global__ void k_attcoef(const float* __restrict__ h, const float* __restrict__ Wsrc,
                          const float* __restrict__ Wdst, float* __restrict__ asrc,
                          float* __restrict__ adst, int n){
    int i = blockIdx.x * blockDim.x + threadIdx.x;
    if (i >= n) return;
    const float4* h4 = (const float4*)(h + (size_t)i * 64);
    const float4* ws4 = (const float4*)Wsrc;
    const float4* wd4 = (const float4*)Wdst;
    float4 s = {0,0,0,0}, d = {0,0,0,0};
    #pragma unroll
    for (int k4 = 0; k4 < 16; k4++){
        float4 hv = h4[k4];
        float4 w;
        w = ws4[k4*4+0]; s.x += hv.x*w.x; s.y += hv.x*w.y; s.z += hv.x*w.z; s.w += hv.x*w.w;
        w = ws4[k4*4+1]; s.x += hv.y*w.x; s.y += hv.y*w.y; s.z += hv.y*w.z; s.w += hv.y*w.w;
        w = ws4[k4*4+2]; s.x += hv.z*w.x; s.y += hv.z*w.y; s.z += hv.z*w.z; s.w += hv.z*w.w;
        w = ws4[k4*4+3]; s.x += hv.w*w.x; s.y += hv.w*w.y; s.z += hv.w*w.z; s.w += hv.w*w.w;
        w = wd4[k4*4+0]; d.x += hv.x*w.x; d.y += hv.x*w.y; d.z += hv.x*w.z; d.w += hv.x*w.w;
        w = wd4[k4*4+1]; d.x += hv.y*w.x; d.y += hv.y*w.y; d.z += hv.y*w.z; d.w += hv.y*w.w;
        w = wd4[k4*4+2]; d.x += hv.z*w.x; d.y += hv.z*w.y; d.z += hv.z*w.z; d.w += hv.z*w.w;
        w = wd4[k4*4+3]; d.x += hv.w*w.x; d.y += hv.w*w.y; d.z += hv.w*w.z; d.w += hv.w*w.w;
    }
    ((float4*)asrc)[i] = s;
    ((float4*)adst)[i] = d;
}

// ---------------- per-node online segment-softmax aggregation (wave per node) ----------------
// agg[i][h*64+k] = (sum_e alpha_eh * h[src_e][k]) / (ssum_h + 1e-16), including self-loop.
__global__ void k_aggregate(const float* __restrict__ hin,
                            const float* __restrict__ asrc, const float* __restrict__ adst,
                            const int* __restrict__ row_ptr, const int* __restrict__ col_src,
                            const int* __restrict__ col_eid, const float* __restrict__ ea,
                            const double* __restrict__ Mm, const double* __restrict__ ael,
                            float* __restrict__ agg, int n){
    int w = threadIdx.x >> 6, lane = threadIdx.x & 63;
    int i = blockIdx.x * 4 + w;
    if (i >= n) return;

    double M0[4], M1[4], M2[4], ae_loop[4];
    #pragma unroll
    for (int h = 0; h < 4; h++){
        M0[h] = Mm[0*4 + h]; M1[h] = Mm[1*4 + h]; M2[h] = Mm[2*4 + h];
        ae_loop[h] = ael[h];
    }

    float4 asv = ((const float4*)asrc)[i];
    float4 adv = ((const float4*)adst)[i];
    float as_i[4] = {asv.x, asv.y, asv.z, asv.w};
    float ad_i[4] = {adv.x, adv.y, adv.z, adv.w};

    float hself = hin[(size_t)i*64 + lane];
    double m[4]; float ssum[4], acc[4];
    #pragma unroll
    for (int h = 0; h < 4; h++){
        double dd = (double)as_i[h] + (double)ad_i[h] + ae_loop[h];
        if (dd < 0.0) dd *= 0.2;
        m[h] = dd; ssum[h] = 1.0f; acc[h] = hself;   // self-loop: p = exp(0) = 1
    }

    int r0 = row_ptr[i], r1 = row_ptr[i+1];
    for (int e = r0; e < r1; e++){
        int s   = col_src[e];
        int eid = col_eid[e];
        float hv = hin[(size_t)s*64 + lane];
        float e0 = ea[eid*3+0], e1 = ea[eid*3+1], e2 = ea[eid*3+2];
        double e2m = 1.0e6 / (double)e2;
        float4 av = ((const float4*)asrc)[s];
        float as_s[4] = {av.x, av.y, av.z, av.w};
        #pragma unroll
        for (int h = 0; h < 4; h++){
            double aeh = (double)e0*M0[h] + (double)e1*M1[h] + e2m*M2[h];
            double dd = (double)as_s[h] + (double)ad_i[h] + aeh;
            if (dd < 0.0) dd *= 0.2;             // leaky_relu 0.2
            if (dd <= m[h]){
                float p = expf((float)(dd - m[h]));
                ssum[h] += p;
                acc[h] += p * hv;
            } else {
                float sc = expf((float)(m[h] - dd));
                ssum[h] = ssum[h]*sc + 1.0f;
                acc[h]  = acc[h]*sc + hv;
                m[h] = dd;
            }
        }
    }
    #pragma unroll
    for (int h = 0; h < 4; h++){
        float inv = 1.0f / (ssum[h] + 1e-16f);
        agg[(size_t)i*256 + h*64 + lane] = acc[h] * inv;
    }
}

// ---------------- tiled GEMM: out[n,64] = act(A[n,K] @ B[K,64] + bias (+res)) ----------------
template<int K, bool RES, bool GEL>
__global__ void __launch_bounds__(256) k_gemm(const float* __restrict__ A, const float* __restrict__ B,
                      const float* __restrict__ bias, const float* __restrict__ res,
                      float* __restrict__ out, int n){
    __shared__ float Bs[K * 64];
    int t = threadIdx.x;
    for (int idx = t; idx < K*64; idx += 256) Bs[idx] = B[idx];
    __syncthreads();

    int row0 = blockIdx.x * 64;
    int tr = t >> 4, tc = t & 15;
    int r = row0 + tr*4;
    int c = tc*4;
    float acc[4][4] = {};

    int rr[4];
    #pragma unroll
    for (int i = 0; i < 4; i++){ int q = r + i; rr[i] = (q < n) ? q : (n - 1); }

    const float4* A4 = (const float4*)A;
    for (int k4 = 0; k4 < K/4; k4++){
        float4 b0 = *(const float4*)&Bs[(k4*4+0)*64 + c];
        float4 b1 = *(const float4*)&Bs[(k4*4+1)*64 + c];
        float4 b2 = *(const float4*)&Bs[(k4*4+2)*64 + c];
        float4 b3 = *(const float4*)&Bs[(k4*4+3)*64 + c];
        #pragma unroll
        for (int i = 0; i < 4; i++){
            float4 a = A4[(size_t)rr[i]*(K/4) + k4];
            acc[i][0] += a.x*b0.x + a.y*b1.x + a.z*b2.x + a.w*b3.x;
            acc[i][1] += a.x*b0.y + a.y*b1.y + a.z*b2.y + a.w*b3.y;
            acc[i][2] += a.x*b0.z + a.y*b1.z + a.z*b2.z + a.w*b3.z;
            acc[i][3] += a.x*b0.w + a.y*b1.w + a.z*b2.w + a.w*b3.w;
        }
    }

    float4 bb = *(const float4*)&bias[c];
    #pragma unroll
    for (int i = 0; i < 4; i++){
        int q = r + i;
        if (q < n){
            float4 v;
            v.x = acc[i][0] + bb.x; v.y = acc[i][1] + bb.y;
            v.z = acc[i][2] + bb.z; v.w = acc[i][3] + bb.w;
            if (RES){
                float4 rv = *(const float4*)&res[(size_t)q*64 + c];
                v.x += rv.x; v.y += rv.y; v.z += rv.z; v.w += rv.w;
            }
            if (GEL){
                v.x = gelu_f(v.x); v.y = gelu_f(v.y);
                v.z = gelu_f(v.z); v.w = gelu_f(v.w);
            }
            *(float4*)&out[(size_t)q*64 + c] = v;
        }
    }
}

// ---------------- fc3 + per-graph min (encoded atomicMin) ----------------
__global__ void k_fc3(const float* __restrict__ h, const float* __restrict__ W,
                      const float* __restrict__ b, const int* __restrict__ batch,
                      unsigned int* __restrict__ qenc, int n){
    int i = blockIdx.x * blockDim.x + threadIdx.x;
    if (i >= n) return;
    float q = b[0];
    const float4* h4 = (const float4*)(h + (size_t)i*64);
    const float4* w4 = (const float4*)W;
    #pragma unroll
    for (int k = 0; k < 16; k++){
        float4 hv = h4[k], wv = w4[k];
        q += hv.x*wv.x + hv.y*wv.y + hv.z*wv.z + hv.w*wv.w;
    }
    unsigned u = __float_as_uint(q);
    u = (u & 0x80000000u) ? ~u : (u | 0x80000000u);   // order-preserving encode
    atomicMin(&qenc[batch[i]], u);
}

__global__ void k_qout(const unsigned int* __restrict__ qenc, float* __restrict__ out){
    int g = threadIdx.x;
    unsigned u = qenc[g];
    u = (u & 0x80000000u) ? (u & 0x7FFFFFFFu) : ~u;   // decode
    out[g] = __uint_as_float(u);
}

extern "C" void kernel_launch(void* const* d_in, const int* in_sizes, int n_in,
                              void* d_out, int out_size, void* d_ws, size_t ws_size,
                              hipStream_t stream){
    const float* x     = (const float*)d_in[0];
    const int*   ei    = (const int*)  d_in[1];
    const float* ea    = (const float*)d_in[2];
    const int*   batch = (const int*)  d_in[3];
    const float* linW  = (const float*)d_in[4];
    const float* linb  = (const float*)d_in[5];
    const float* convW = (const float*)d_in[6];
    const float* attS  = (const float*)d_in[7];
    const float* attD  = (const float*)d_in[8];
    const float* We    = (const float*)d_in[9];
    const float* attE  = (const float*)d_in[10];
    const float* convb = (const float*)d_in[11];
    const float* fc1W  = (const float*)d_in[12];
    const float* fc1b  = (const float*)d_in[13];
    const float* fc2W  = (const float*)d_in[14];
    const float* fc2b  = (const float*)d_in[15];
    const float* fc3W  = (const float*)d_in[16];
    const float* fc3b  = (const float*)d_in[17];

    int N = in_sizes[0] / 15;
    int E = in_sizes[1] / 2;

    char* w = (char*)d_ws;
    size_t o = 0;
    auto alloc = [&](size_t bytes) -> char* {
        char* p = w + o;
        o = (o + bytes + 255) & ~(size_t)255;
        return p;
    };
    double*   dsum   = (double*)  alloc(4 * 8);
    double*   Mm     = (double*)  alloc(2 * 12 * 8);
    double*   ael    = (double*)  alloc(2 * 4 * 8);
    float*    Wsrc   = (float*)   alloc(2 * 64 * 4 * 4);
    float*    Wdst   = (float*)   alloc(2 * 64 * 4 * 4);
    float*    Wt     = (float*)   alloc(2 * 256 * 64 * 4);
    unsigned* qenc   = (unsigned*)alloc(64 * 4);
    int*      deg    = (int*)     alloc((size_t)N * 4);
    int*      cursor = (int*)     alloc((size_t)N * 4);
    int*      rowptr = (int*)     alloc((size_t)(N + 1) * 4);
    int*      csum   = (int*)     alloc(64 * 4);
    int*      coff   = (int*)     alloc(64 * 4);
    int*      colsrc = (int*)     alloc((size_t)E * 4);
    int*      coleid = (int*)     alloc((size_t)E * 4);
    float*    asrc   = (float*)   alloc((size_t)N * 16);
    float*    adst   = (float*)   alloc((size_t)N * 16);
    float*    hA     = (float*)   alloc((size_t)N * 256);
    float*    hB     = (float*)   alloc((size_t)N * 256);
    float*    agg    = (float*)   alloc((size_t)N * 1024);
    (void)ws_size; (void)n_in; (void)out_size;

    hipMemsetAsync(dsum, 0, 4 * 8, stream);
    hipMemsetAsync(deg, 0, (size_t)N * 4, stream);
    hipMemsetAsync(qenc, 0xFF, 64 * 4, stream);

    int nchunk = (N + 1023) / 1024;

    k_edge_stats<<<1024, 256, 0, stream>>>(ei, ea, E, dsum, deg);
    k_params<<<1, 256, 0, stream>>>(dsum, E, convW, attS, attD, We, attE, Mm, ael, Wsrc, Wdst, Wt);
    k_chunk_sum<<<nchunk, 256, 0, stream>>>(deg, N, csum);
    k_chunk_scan<<<1, 64, 0, stream>>>(csum, nchunk, coff, rowptr + N);
    k_row_ptr<<<nchunk, 1024, 0, stream>>>(deg, N, coff, rowptr, cursor);
    k_scatter<<<1024, 256, 0, stream>>>(ei, E, cursor, colsrc, coleid);

    k_lin_in<<<(N + 3) / 4, 256, 0, stream>>>(x, linW, linb, hA, N);

    // layer 0 (no residual)
    k_attcoef<<<(N + 255) / 256, 256, 0, stream>>>(hA, Wsrc, Wdst, asrc, adst, N);
    k_aggregate<<<(N + 3) / 4, 256, 0, stream>>>(hA, asrc, adst, rowptr, colsrc, coleid, ea,
                                                 Mm, ael, agg, N);
    k_gemm<256, false, true><<<(N + 63) / 64, 256, 0, stream>>>(agg, Wt, convb, nullptr, hB, N);

    // layer 1 (residual)
    k_attcoef<<<(N + 255) / 256, 256, 0, stream>>>(hB, Wsrc + 256, Wdst + 256, asrc, adst, N);
    k_aggregate<<<(N + 3) / 4, 256, 0, stream>>>(hB, asrc, adst, rowptr, colsrc, coleid, ea,
                                                 Mm + 12, ael + 4, agg, N);
    k_gemm<256, true, true><<<(N + 63) / 64, 256, 0, stream>>>(agg, Wt + 16384, convb + 64, hB, hA, N);

    // fc head
    k_gemm<64, false, true><<<(N + 63) / 64, 256, 0, stream>>>(hA, fc1W, fc1b, nullptr, hB, N);
    k_gemm<64, false, true><<<(N + 63) / 64, 256, 0, stream>>>(hB, fc2W, fc2b, nullptr, hA, N);
    k_fc3<<<(N + 255) / 256, 256, 0, stream>>>(hA, fc3W, fc3b, batch, qenc, N);
    k_qout<<<1, 64, 0, stream>>>(qenc, (float*)d_out);
}

// Round 2
// 516.557 us; speedup vs baseline: 1.5171x; 1.5171x over previous
//
#include <hip/hip_runtime.h>
#include <math.h>

// GraphQNetwork: 2-layer GAT (H=4 heads, C=64, concat=False/head-mean) + 3 FC + per-graph min.
// N=50000, E=400000, NG=64 (derived from in_sizes at launch).

__device__ __forceinline__ float gelu_f(float x){
    return 0.5f * x * (1.0f + erff(x * 0.70710678118654752f));
}

// ---------------- edge stats (mean of modified edge_attr) + in-degree histogram ----------------
__global__ void k_edge_stats(const int* __restrict__ ei, const float* __restrict__ ea,
                             int E, double* __restrict__ dsum, int* __restrict__ deg){
    __shared__ double s0[256], s1[256], s2[256];
    int t = threadIdx.x;
    double a0 = 0, a1 = 0, a2 = 0;
    for (int e = blockIdx.x * blockDim.x + t; e < E; e += gridDim.x * blockDim.x){
        float e0 = ea[e*3+0], e1 = ea[e*3+1], e2 = ea[e*3+2];
        a0 += (double)e0;
        a1 += (double)e1;
        a2 += 1.0e6 / (double)e2;   // in-place edit: 1e6 / spectral_efficiency
        atomicAdd(&deg[ei[E + e]], 1);   // dst = edge_index[1]
    }
    s0[t] = a0; s1[t] = a1; s2[t] = a2;
    __syncthreads();
    for (int off = 128; off > 0; off >>= 1){
        if (t < off){ s0[t] += s0[t+off]; s1[t] += s1[t+off]; s2[t] += s2[t+off]; }
        __syncthreads();
    }
    if (t == 0){
        atomicAdd(&dsum[0], s0[0]);
        atomicAdd(&dsum[1], s1[0]);
        atomicAdd(&dsum[2], s2[0]);
    }
}

// ---------------- tiny parameter precompute ----------------
__global__ void k_params(const double* __restrict__ dsum, int E,
                         const float* __restrict__ convW, const float* __restrict__ attS,
                         const float* __restrict__ attD, const float* __restrict__ We,
                         const float* __restrict__ attE,
                         double* __restrict__ Mm, double* __restrict__ ael,
                         float* __restrict__ Wsrc, float* __restrict__ Wdst,
                         float* __restrict__ Wt){
    int t = threadIdx.x;
    if (t < 24){
        int l = t / 12, r = t % 12, j = r / 4, h = r % 4;
        double s = 0;
        for (int c = 0; c < 64; c++)
            s += (double)We[l*768 + j*256 + h*64 + c] * (double)attE[l*256 + h*64 + c];
        Mm[l*12 + j*4 + h] = s;
    }
    __syncthreads();
    if (t < 8){
        int l = t / 4, h = t % 4;
        double s = 0;
        for (int j = 0; j < 3; j++)
            s += (dsum[j] / (double)E) * Mm[l*12 + j*4 + h];
        ael[l*4 + h] = s;
    }
    for (int idx = t; idx < 512; idx += 256){
        int l = idx >> 8, k = (idx >> 2) & 63, h = idx & 3;
        float ss = 0.f, sd = 0.f;
        for (int c = 0; c < 64; c++){
            float wv = convW[l*16384 + k*256 + h*64 + c];
            ss += wv * attS[l*256 + h*64 + c];
            sd += wv * attD[l*256 + h*64 + c];
        }
        Wsrc[idx] = ss; Wdst[idx] = sd;
    }
    for (int idx = t; idx < 32768; idx += 256){
        int l = idx >> 14, p = (idx >> 6) & 255, c = idx & 63;
        int h = p >> 6, k = p & 63;
        Wt[idx] = 0.25f * convW[l*16384 + k*256 + h*64 + c];
    }
}

// ---------------- CSR build ----------------
__global__ void k_chunk_sum(const int* __restrict__ deg, int n, int* __restrict__ csum){
    __shared__ int s[256];
    int t = threadIdx.x, base = blockIdx.x * 1024;
    int v = 0;
    for (int j = t; j < 1024; j += 256){ int i = base + j; if (i < n) v += deg[i]; }
    s[t] = v; __syncthreads();
    for (int off = 128; off > 0; off >>= 1){ if (t < off) s[t] += s[t+off]; __syncthreads(); }
    if (t == 0) csum[blockIdx.x] = s[0];
}

__global__ void k_chunk_scan(const int* __restrict__ csum, int nchunks,
                             int* __restrict__ coff, int* __restrict__ rp_end){
    if (threadIdx.x == 0){
        int run = 0;
        for (int i = 0; i < nchunks; i++){ coff[i] = run; run += csum[i]; }
        *rp_end = run;
    }
}

__global__ void __launch_bounds__(1024) k_row_ptr(const int* __restrict__ deg, int n,
                          const int* __restrict__ coff,
                          int* __restrict__ row_ptr, int* __restrict__ cursor){
    __shared__ int s[1024];
    int t = threadIdx.x, i = blockIdx.x * 1024 + t;
    int v = (i < n) ? deg[i] : 0;
    s[t] = v; __syncthreads();
    for (int off = 1; off < 1024; off <<= 1){
        int x = (t >= off) ? s[t-off] : 0;
        __syncthreads();
        s[t] += x;
        __syncthreads();
    }
    if (i < n){
        int e = coff[blockIdx.x] + s[t] - v;   // exclusive
        row_ptr[i] = e; cursor[i] = e;
    }
}

__global__ void k_scatter(const int* __restrict__ ei, int E, int* __restrict__ cursor,
                          int* __restrict__ col_src, int* __restrict__ col_eid){
    for (int e = blockIdx.x * blockDim.x + threadIdx.x; e < E; e += gridDim.x * blockDim.x){
        int d = ei[E + e];
        int pos = atomicAdd(&cursor[d], 1);
        col_src[pos] = ei[e];
        col_eid[pos] = e;
    }
}

// ---------------- per-edge attention logit contribution (per layer), CSR order ----------------
// ae[p][h] = e0*M[0][h] + e1*M[1][h] + (1e6/e2)*M[2][h]   (double, matches reference math)
__global__ void k_edge_ae(const int* __restrict__ col_eid, const float* __restrict__ ea,
                          const double* __restrict__ Mm, double4* __restrict__ ae, int E){
    int p = blockIdx.x * blockDim.x + threadIdx.x;
    if (p >= E) return;
    int e = col_eid[p];
    double e0 = (double)ea[e*3+0];
    double e1 = (double)ea[e*3+1];
    double e2m = 1.0e6 / (double)ea[e*3+2];
    double4 v;
    v.x = e0*Mm[0] + e1*Mm[4] + e2m*Mm[8];
    v.y = e0*Mm[1] + e1*Mm[5] + e2m*Mm[9];
    v.z = e0*Mm[2] + e1*Mm[6] + e2m*Mm[10];
    v.w = e0*Mm[3] + e1*Mm[7] + e2m*Mm[11];
    ae[p] = v;
}

// ---------------- input projection: h = gelu(x @ linW + linb), D_IN=15 ----------------
__global__ void k_lin_in(const float* __restrict__ x, const float* __restrict__ W,
                         const float* __restrict__ b, float* __restrict__ h, int n){
    int t = threadIdx.x;
    int row = blockIdx.x * 4 + (t >> 6);
    int c = t & 63;
    if (row >= n) return;
    float acc = b[c];
    #pragma unroll
    for (int j = 0; j < 15; j++) acc += x[row*15 + j] * W[j*64 + c];
    h[row*64 + c] = gelu_f(acc);
}

// ---------------- attention coefficients: a_src/a_dst = h @ Wsrc/Wdst ([64,4]) ----------------
__global__ void k_attcoef(const float* __restrict__ h, const float* __restrict__ Wsrc,
                          const float* __restrict__ Wdst, float* __restrict__ asrc,
                          float* __restrict__ adst, int n){
    int i = blockIdx.x * blockDim.x + threadIdx.x;
    if (i >= n) return;
    const float4* h4 = (const float4*)(h + (size_t)i * 64);
    const float4* ws4 = (const float4*)Wsrc;
    const float4* wd4 = (const float4*)Wdst;
    float4 s = {0,0,0,0}, d = {0,0,0,0};
    #pragma unroll
    for (int k4 = 0; k4 < 16; k4++){
        float4 hv = h4[k4];
        float4 w;
        w = ws4[k4*4+0]; s.x += hv.x*w.x; s.y += hv.x*w.y; s.z += hv.x*w.z; s.w += hv.x*w.w;
        w = ws4[k4*4+1]; s.x += hv.y*w.x; s.y += hv.y*w.y; s.z += hv.y*w.z; s.w += hv.y*w.w;
        w = ws4[k4*4+2]; s.x += hv.z*w.x; s.y += hv.z*w.y; s.z += hv.z*w.z; s.w += hv.z*w.w;
        w = ws4[k4*4+3]; s.x += hv.w*w.x; s.y += hv.w*w.y; s.z += hv.w*w.z; s.w += hv.w*w.w;
        w = wd4[k4*4+0]; d.x += hv.x*w.x; d.y += hv.x*w.y; d.z += hv.x*w.z; d.w += hv.x*w.w;
        w = wd4[k4*4+1]; d.x += hv.y*w.x; d.y += hv.y*w.y; d.z += hv.y*w.z; d.w += hv.y*w.w;
        w = wd4[k4*4+2]; d.x += hv.z*w.x; d.y += hv.z*w.y; d.z += hv.z*w.z; d.w += hv.z*w.w;
        w = wd4[k4*4+3]; d.x += hv.w*w.x; d.y += hv.w*w.y; d.z += hv.w*w.z; d.w += hv.w*w.w;
    }
    ((float4*)asrc)[i] = s;
    ((float4*)adst)[i] = d;
}

// ---------------- per-node online segment-softmax aggregation (wave per node) ----------------
__global__ void k_aggregate(const float* __restrict__ hin,
                            const float* __restrict__ asrc, const float* __restrict__ adst,
                            const int* __restrict__ row_ptr, const int* __restrict__ col_src,
                            const double4* __restrict__ ae,
                            const double* __restrict__ ael,
                            float* __restrict__ agg, int n){
    int w = threadIdx.x >> 6, lane = threadIdx.x & 63;
    int i = blockIdx.x * 4 + w;
    if (i >= n) return;

    float4 asv = ((const float4*)asrc)[i];
    float4 adv = ((const float4*)adst)[i];
    float as_i[4] = {asv.x, asv.y, asv.z, asv.w};
    float ad_i[4] = {adv.x, adv.y, adv.z, adv.w};

    float hself = hin[(size_t)i*64 + lane];
    double m[4]; float ssum[4], acc[4];
    #pragma unroll
    for (int h = 0; h < 4; h++){
        double dd = (double)as_i[h] + (double)ad_i[h] + ael[h];
        if (dd < 0.0) dd *= 0.2;
        m[h] = dd; ssum[h] = 1.0f; acc[h] = hself;   // self-loop: p = exp(0) = 1
    }

    int r0 = row_ptr[i], r1 = row_ptr[i+1];
    for (int e = r0; e < r1; e++){
        int s = col_src[e];
        float hv = hin[(size_t)s*64 + lane];
        double4 aev = ae[e];
        double aeh[4] = {aev.x, aev.y, aev.z, aev.w};
        float4 av = ((const float4*)asrc)[s];
        float as_s[4] = {av.x, av.y, av.z, av.w};
        #pragma unroll
        for (int h = 0; h < 4; h++){
            double dd = (double)as_s[h] + (double)ad_i[h] + aeh[h];
            if (dd < 0.0) dd *= 0.2;             // leaky_relu 0.2
            if (dd <= m[h]){
                float p = expf((float)(dd - m[h]));
                ssum[h] += p;
                acc[h] += p * hv;
            } else {
                float sc = expf((float)(m[h] - dd));
                ssum[h] = ssum[h]*sc + 1.0f;
                acc[h]  = acc[h]*sc + hv;
                m[h] = dd;
            }
        }
    }
    #pragma unroll
    for (int h = 0; h < 4; h++){
        float inv = 1.0f / (ssum[h] + 1e-16f);
        agg[(size_t)i*256 + h*64 + lane] = acc[h] * inv;
    }
}

// ---------------- tiled GEMM: out[n,64] = act(A[n,K] @ B[K,64] + bias (+res)) ----------------
template<int K, bool RES, bool GEL>
__global__ void __launch_bounds__(256) k_gemm(const float* __restrict__ A, const float* __restrict__ B,
                      const float* __restrict__ bias, const float* __restrict__ res,
                      float* __restrict__ out, int n){
    __shared__ float Bs[K * 64];
    int t = threadIdx.x;
    for (int idx = t; idx < K*64; idx += 256) Bs[idx] = B[idx];
    __syncthreads();

    int row0 = blockIdx.x * 64;
    int tr = t >> 4, tc = t & 15;
    int r = row0 + tr*4;
    int c = tc*4;
    float acc[4][4] = {};

    int rr[4];
    #pragma unroll
    for (int i = 0; i < 4; i++){ int q = r + i; rr[i] = (q < n) ? q : (n - 1); }

    const float4* A4 = (const float4*)A;
    for (int k4 = 0; k4 < K/4; k4++){
        float4 b0 = *(const float4*)&Bs[(k4*4+0)*64 + c];
        float4 b1 = *(const float4*)&Bs[(k4*4+1)*64 + c];
        float4 b2 = *(const float4*)&Bs[(k4*4+2)*64 + c];
        float4 b3 = *(const float4*)&Bs[(k4*4+3)*64 + c];
        #pragma unroll
        for (int i = 0; i < 4; i++){
            float4 a = A4[(size_t)rr[i]*(K/4) + k4];
            acc[i][0] += a.x*b0.x + a.y*b1.x + a.z*b2.x + a.w*b3.x;
            acc[i][1] += a.x*b0.y + a.y*b1.y + a.z*b2.y + a.w*b3.y;
            acc[i][2] += a.x*b0.z + a.y*b1.z + a.z*b2.z + a.w*b3.z;
            acc[i][3] += a.x*b0.w + a.y*b1.w + a.z*b2.w + a.w*b3.w;
        }
    }

    float4 bb = *(const float4*)&bias[c];
    #pragma unroll
    for (int i = 0; i < 4; i++){
        int q = r + i;
        if (q < n){
            float4 v;
            v.x = acc[i][0] + bb.x; v.y = acc[i][1] + bb.y;
            v.z = acc[i][2] + bb.z; v.w = acc[i][3] + bb.w;
            if (RES){
                float4 rv = *(const float4*)&res[(size_t)q*64 + c];
                v.x += rv.x; v.y += rv.y; v.z += rv.z; v.w += rv.w;
            }
            if (GEL){
                v.x = gelu_f(v.x); v.y = gelu_f(v.y);
                v.z = gelu_f(v.z); v.w = gelu_f(v.w);
            }
            *(float4*)&out[(size_t)q*64 + c] = v;
        }
    }
}

// ---------------- fc3 + per-graph min (hierarchical: wave -> LDS -> global) ----------------
__global__ void k_fc3(const float* __restrict__ h, const float* __restrict__ W,
                      const float* __restrict__ b, const int* __restrict__ batch,
                      unsigned int* __restrict__ qenc, int n){
    __shared__ unsigned smin[64];
    int t = threadIdx.x;
    if (t < 64) smin[t] = 0xFFFFFFFFu;
    __syncthreads();

    int i = blockIdx.x * blockDim.x + t;
    unsigned u = 0xFFFFFFFFu;
    int g = -1;
    if (i < n){
        float q = b[0];
        const float4* h4 = (const float4*)(h + (size_t)i*64);
        const float4* w4 = (const float4*)W;
        #pragma unroll
        for (int k = 0; k < 16; k++){
            float4 hv = h4[k], wv = w4[k];
            q += hv.x*wv.x + hv.y*wv.y + hv.z*wv.z + hv.w*wv.w;
        }
        unsigned enc = __float_as_uint(q);
        u = (enc & 0x80000000u) ? ~enc : (enc | 0x80000000u);   // order-preserving encode
        g = batch[i];
    }
    int g0 = __shfl(g, 0);
    bool uni = __all(g == g0);
    if (uni){
        // batch sorted: the whole wave is usually one graph -> register reduce
        #pragma unroll
        for (int off = 32; off > 0; off >>= 1){
            unsigned o = __shfl_xor(u, off);
            u = (o < u) ? o : u;
        }
        if ((t & 63) == 0 && g0 >= 0) atomicMin(&smin[g0], u);
    } else if (i < n){
        atomicMin(&smin[g], u);
    }
    __syncthreads();
    if (t < 64 && smin[t] != 0xFFFFFFFFu) atomicMin(&qenc[t], smin[t]);
}

__global__ void k_qout(const unsigned int* __restrict__ qenc, float* __restrict__ out){
    int g = threadIdx.x;
    unsigned u = qenc[g];
    u = (u & 0x80000000u) ? (u & 0x7FFFFFFFu) : ~u;   // decode
    out[g] = __uint_as_float(u);
}

extern "C" void kernel_launch(void* const* d_in, const int* in_sizes, int n_in,
                              void* d_out, int out_size, void* d_ws, size_t ws_size,
                              hipStream_t stream){
    const float* x     = (const float*)d_in[0];
    const int*   ei    = (const int*)  d_in[1];
    const float* ea    = (const float*)d_in[2];
    const int*   batch = (const int*)  d_in[3];
    const float* linW  = (const float*)d_in[4];
    const float* linb  = (const float*)d_in[5];
    const float* convW = (const float*)d_in[6];
    const float* attS  = (const float*)d_in[7];
    const float* attD  = (const float*)d_in[8];
    const float* We    = (const float*)d_in[9];
    const float* attE  = (const float*)d_in[10];
    const float* convb = (const float*)d_in[11];
    const float* fc1W  = (const float*)d_in[12];
    const float* fc1b  = (const float*)d_in[13];
    const float* fc2W  = (const float*)d_in[14];
    const float* fc2b  = (const float*)d_in[15];
    const float* fc3W  = (const float*)d_in[16];
    const float* fc3b  = (const float*)d_in[17];

    int N = in_sizes[0] / 15;
    int E = in_sizes[1] / 2;

    char* w = (char*)d_ws;
    size_t o = 0;
    auto alloc = [&](size_t bytes) -> char* {
        char* p = w + o;
        o = (o + bytes + 255) & ~(size_t)255;
        return p;
    };
    double*   dsum   = (double*)  alloc(4 * 8);
    double*   Mm     = (double*)  alloc(2 * 12 * 8);
    double*   ael    = (double*)  alloc(2 * 4 * 8);
    float*    Wsrc   = (float*)   alloc(2 * 64 * 4 * 4);
    float*    Wdst   = (float*)   alloc(2 * 64 * 4 * 4);
    float*    Wt     = (float*)   alloc(2 * 256 * 64 * 4);
    unsigned* qenc   = (unsigned*)alloc(64 * 4);
    int*      deg    = (int*)     alloc((size_t)N * 4);
    int*      cursor = (int*)     alloc((size_t)N * 4);
    int*      rowptr = (int*)     alloc((size_t)(N + 1) * 4);
    int*      csum   = (int*)     alloc(64 * 4);
    int*      coff   = (int*)     alloc(64 * 4);
    int*      colsrc = (int*)     alloc((size_t)E * 4);
    int*      coleid = (int*)     alloc((size_t)E * 4);
    double4*  aebuf  = (double4*) alloc((size_t)E * 32);
    float*    asrc   = (float*)   alloc((size_t)N * 16);
    float*    adst   = (float*)   alloc((size_t)N * 16);
    float*    hA     = (float*)   alloc((size_t)N * 256);
    float*    hB     = (float*)   alloc((size_t)N * 256);
    float*    agg    = (float*)   alloc((size_t)N * 1024);
    (void)ws_size; (void)n_in; (void)out_size;

    hipMemsetAsync(dsum, 0, 4 * 8, stream);
    hipMemsetAsync(deg, 0, (size_t)N * 4, stream);
    hipMemsetAsync(qenc, 0xFF, 64 * 4, stream);

    int nchunk = (N + 1023) / 1024;

    k_edge_stats<<<1024, 256, 0, stream>>>(ei, ea, E, dsum, deg);
    k_params<<<1, 256, 0, stream>>>(dsum, E, convW, attS, attD, We, attE, Mm, ael, Wsrc, Wdst, Wt);
    k_chunk_sum<<<nchunk, 256, 0, stream>>>(deg, N, csum);
    k_chunk_scan<<<1, 64, 0, stream>>>(csum, nchunk, coff, rowptr + N);
    k_row_ptr<<<nchunk, 1024, 0, stream>>>(deg, N, coff, rowptr, cursor);
    k_scatter<<<1024, 256, 0, stream>>>(ei, E, cursor, colsrc, coleid);

    k_lin_in<<<(N + 3) / 4, 256, 0, stream>>>(x, linW, linb, hA, N);

    // layer 0 (no residual)
    k_edge_ae<<<(E + 255) / 256, 256, 0, stream>>>(coleid, ea, Mm, aebuf, E);
    k_attcoef<<<(N + 255) / 256, 256, 0, stream>>>(hA, Wsrc, Wdst, asrc, adst, N);
    k_aggregate<<<(N + 3) / 4, 256, 0, stream>>>(hA, asrc, adst, rowptr, colsrc, aebuf,
                                                 ael, agg, N);
    k_gemm<256, false, true><<<(N + 63) / 64, 256, 0, stream>>>(agg, Wt, convb, nullptr, hB, N);

    // layer 1 (residual)
    k_edge_ae<<<(E + 255) / 256, 256, 0, stream>>>(coleid, ea, Mm + 12, aebuf, E);
    k_attcoef<<<(N + 255) / 256, 256, 0, stream>>>(hB, Wsrc + 256, Wdst + 256, asrc, adst, N);
    k_aggregate<<<(N + 3) / 4, 256, 0, stream>>>(hB, asrc, adst, rowptr, colsrc, aebuf,
                                                 ael + 4, agg, N);
    k_gemm<256, true, true><<<(N + 63) / 64, 256, 0, stream>>>(agg, Wt + 16384, convb + 64, hB, hA, N);

    // fc head
    k_gemm<64, false, true><<<(N + 63) / 64, 256, 0, stream>>>(hA, fc1W, fc1b, nullptr, hB, N);
    k_gemm<64, false, true><<<(N + 63) / 64, 256, 0, stream>>>(hB, fc2W, fc2b, nullptr, hA, N);
    k_fc3<<<(N + 255) / 256, 256, 0, stream>>>(hA, fc3W, fc3b, batch, qenc, N);
    k_qout<<<1, 64, 0, stream>>>(qenc, (float*)d_out);
}